// Round 3
// baseline (751.038 us; speedup 1.0000x reference)
//
#include <hip/hip_runtime.h>

typedef float f32x4 __attribute__((ext_vector_type(4)));
typedef float f32x16 __attribute__((ext_vector_type(16)));
typedef __bf16 bf16x8 __attribute__((ext_vector_type(8)));
typedef unsigned u32x4 __attribute__((ext_vector_type(4)));

__device__ __forceinline__ unsigned f2mono(float f) {
  unsigned u = __float_as_uint(f);
  return (u & 0x80000000u) ? ~u : (u | 0x80000000u);
}
__device__ __forceinline__ float mono2f(unsigned u) {
  return (u & 0x80000000u) ? __uint_as_float(u & 0x7fffffffu) : __uint_as_float(~u);
}
__device__ __forceinline__ float lrelu(float x) { return fmaxf(x, 0.2f * x); }
__device__ __forceinline__ unsigned pkhh(unsigned a, unsigned b) {
  return (a >> 16) | (b & 0xffff0000u);
}
__device__ __forceinline__ bf16x8 asbf8(u32x4 u) { return __builtin_bit_cast(bf16x8, u); }
__device__ __forceinline__ float truncbf(float x, unsigned& hbits) {
  hbits = __float_as_uint(x) & 0xffff0000u;
  return __uint_as_float(hbits);
}

// ---------------- init: global_feats = mono(-1e9) ----------------
__global__ void sc_init(unsigned* __restrict__ gf, int total4) {
  int i = blockIdx.x * blockDim.x + threadIdx.x;
  if (i < total4) {
    unsigned m = f2mono(-1.0e9f);
    ((uint4*)gf)[i] = make_uint4(m, m, m, m);
  }
}

// ---- fused: gather + L1(MFMA) + L2(split-bf16 MFMA) + running segmented max ----
// Each wave owns ONE contiguous chunk of CPW points (31 tiles of 32). Running
// per-feature max in registers; flush on batch transition. Interior batches
// (exclusively owned by this wave) use plain stores; boundary batches atomicMax.
__global__ __launch_bounds__(256, 4) void sc_main(
    const float* __restrict__ muons, const int* __restrict__ bidx,
    const float* __restrict__ cond, const float* __restrict__ W1,
    const float* __restrict__ b1, const float* __restrict__ W2,
    const float* __restrict__ b2, unsigned* __restrict__ gf, int N, int CPW) {
  __shared__ __align__(16) __bf16 w2h[8192];  // [kc=8][j=128][e=8] blocked, linear reads
  __shared__ __align__(16) __bf16 w2l[8192];
  __shared__ __align__(16) __bf16 w1e[2048];  // [kc=4][j=64][e=8] extended W1 (hi|hi|lo|bias)

  const int t = threadIdx.x;
  const int w = t >> 6;
  const int lane = t & 63;
  const int col = lane & 31;
  const int kh2 = lane >> 5;

  // ---- one-time weight staging ----
  {
    const int j = t & 127, kh = t >> 7;
    for (int kk = 0; kk < 32; ++kk) {
      const int k = kh * 32 + kk;
      const float v = W2[k * 128 + j];
      const __bf16 hb = (__bf16)v;
      const __bf16 lb = (__bf16)(v - (float)hb);
      const int idx = ((k >> 3) * 128 + j) * 8 + (k & 7);
      w2h[idx] = hb;
      w2l[idx] = lb;
    }
  }
  {
    // extended A1[j][k']: k'=0..6 W1h, 7..13 W1h, 14..20 W1l, 21 b1h, 22 b1l, else 0
    const int j = t & 63, kc = t >> 6;
    for (int e = 0; e < 8; ++e) {
      const int kp = kc * 8 + e;
      float val = 0.0f;
      unsigned hb;
      if (kp < 7)        { val = truncbf(W1[kp * 64 + j], hb); }
      else if (kp < 14)  { val = truncbf(W1[(kp - 7) * 64 + j], hb); }
      else if (kp < 21)  { float x = W1[(kp - 14) * 64 + j]; val = x - truncbf(x, hb); }
      else if (kp == 21) { val = truncbf(b1[j], hb); }
      else if (kp == 22) { float x = b1[j]; val = x - truncbf(x, hb); }
      w1e[(kc * 64 + j) * 8 + e] = (__bf16)val;
    }
  }
  __syncthreads();

  // hoisted per-lane statics
  bf16x8 w1f[2][2];
  #pragma unroll
  for (int jt = 0; jt < 2; ++jt)
    #pragma unroll
    for (int mf = 0; mf < 2; ++mf)
      w1f[jt][mf] = *(const bf16x8*)&w1e[(((mf * 2 + kh2) * 64) + jt * 32 + col) * 8];
  float b2v[4];
  #pragma unroll
  for (int jt = 0; jt < 4; ++jt) b2v[jt] = b2[jt * 32 + col];
  f32x16 zf;
  #pragma unroll
  for (int e = 0; e < 16; ++e) zf[e] = 0.0f;

  // ---- chunk setup ----
  const int gwave = blockIdx.x * 4 + w;
  const int start = gwave * CPW;
  if (start >= N) return;
  const int end = min(start + CPW, N);
  const int prevb = (start == 0) ? -1 : bidx[start - 1];
  const int nextb = (end >= N) ? -1 : bidx[end];
  int run_b = bidx[start];
  float run_s[4];
  #pragma unroll
  for (int jt = 0; jt < 4; ++jt) run_s[jt] = -3.0e38f;

  auto FLUSH = [&](int b, const float* m) {
    const bool interior = (b != prevb) && (b != nextb);
    if (lane < 32) {
      #pragma unroll
      for (int jt = 0; jt < 4; ++jt) {
        if (m[jt] > -2.9e38f) {
          const unsigned enc = f2mono(lrelu(m[jt] + b2v[jt]));
          unsigned* addr = &gf[b * 128 + jt * 32 + col];
          if (interior) *addr = enc;
          else atomicMax(addr, enc);
        }
      }
    }
  };

  for (int pbase = start; pbase < end; pbase += 32) {
    const int pc = min(pbase + col, N - 1);
    const int bi = bidx[pc];

    // ---- load + decompose point inputs ----
    float in[7];
    in[0] = muons[pc * 3 + 0];
    in[1] = muons[pc * 3 + 1];
    in[2] = muons[pc * 3 + 2];
    const f32x4 c4 = *(const f32x4*)&cond[bi * 4];
    in[3] = c4.x; in[4] = c4.y; in[5] = c4.z; in[6] = c4.w;
    unsigned hu[7], lu[7];
    #pragma unroll
    for (int f = 0; f < 7; ++f) {
      const float hf = truncbf(in[f], hu[f]);
      lu[f] = __float_as_uint(in[f] - hf);
    }
    // B1 fragments (col = point): K' = [inh(7) | inl(7) | inh(7) | b-slots | 0]
    u32x4 f0a = { pkhh(hu[0], hu[1]), pkhh(hu[2], hu[3]), pkhh(hu[4], hu[5]), pkhh(hu[6], lu[0]) };
    u32x4 f0b = { pkhh(lu[1], lu[2]), pkhh(lu[3], lu[4]), pkhh(lu[5], lu[6]), f0a.x };
    u32x4 f1a = { f0a.y, f0a.z, (hu[6] >> 16) | 0x3F800000u, 0x00003F80u };
    u32x4 bf0u, bf1u;
    #pragma unroll
    for (int e2 = 0; e2 < 4; ++e2) {
      bf0u[e2] = kh2 ? f0b[e2] : f0a[e2];
      bf1u[e2] = kh2 ? 0u : f1a[e2];
    }
    const bf16x8 bfr0 = asbf8(bf0u), bfr1 = asbf8(bf1u);

    // ---- layer1: D1[j][p], bias folded ----
    f32x16 acc0 = __builtin_amdgcn_mfma_f32_32x32x16_bf16(w1f[0][0], bfr0, zf, 0, 0, 0);
    acc0 = __builtin_amdgcn_mfma_f32_32x32x16_bf16(w1f[0][1], bfr1, acc0, 0, 0, 0);
    f32x16 acc1 = __builtin_amdgcn_mfma_f32_32x32x16_bf16(w1f[1][0], bfr0, zf, 0, 0, 0);
    acc1 = __builtin_amdgcn_mfma_f32_32x32x16_bf16(w1f[1][1], bfr1, acc1, 0, 0, 0);

    // ---- lrelu + decompose h into packed bf16 pair-dwords ----
    unsigned pkh_[16], pkl_[16];
    #pragma unroll
    for (int m = 0; m < 8; ++m) {
      const float x0 = lrelu(acc0[2 * m]), x1 = lrelu(acc0[2 * m + 1]);
      unsigned h0, h1;
      const float hf0 = truncbf(x0, h0), hf1 = truncbf(x1, h1);
      const unsigned l0 = __float_as_uint(x0 - hf0), l1 = __float_as_uint(x1 - hf1);
      pkh_[m] = (h0 >> 16) | h1;
      pkl_[m] = (l0 >> 16) | (l1 & 0xffff0000u);
    }
    #pragma unroll
    for (int m = 0; m < 8; ++m) {
      const float x0 = lrelu(acc1[2 * m]), x1 = lrelu(acc1[2 * m + 1]);
      unsigned h0, h1;
      const float hf0 = truncbf(x0, h0), hf1 = truncbf(x1, h1);
      const unsigned l0 = __float_as_uint(x0 - hf0), l1 = __float_as_uint(x1 - hf1);
      pkh_[8 + m] = (h0 >> 16) | h1;
      pkl_[8 + m] = (l0 >> 16) | (l1 & 0xffff0000u);
    }

    // ---- layer2: A-frags assembled in-register via half-wave exchange ----
    f32x16 acc2[4];
    #pragma unroll
    for (int ks = 0; ks < 4; ++ks) {
      const int base = (ks >> 1) * 8;
      const int c0 = (ks & 1) * 4;
      unsigned dh[4], dl[4];
      #pragma unroll
      for (int cc = 0; cc < 2; ++cc) {
        {
          const unsigned plo = pkh_[base + c0 + cc];
          const unsigned phi = pkh_[base + c0 + cc + 2];
          const unsigned x = kh2 ? plo : phi;
          const unsigned y = (unsigned)__shfl_xor((int)x, 32);
          dh[cc] = kh2 ? y : plo;
          dh[2 + cc] = kh2 ? phi : y;
        }
        {
          const unsigned plo = pkl_[base + c0 + cc];
          const unsigned phi = pkl_[base + c0 + cc + 2];
          const unsigned x = kh2 ? plo : phi;
          const unsigned y = (unsigned)__shfl_xor((int)x, 32);
          dl[cc] = kh2 ? y : plo;
          dl[2 + cc] = kh2 ? phi : y;
        }
      }
      const bf16x8 Ah = asbf8((u32x4){dh[0], dh[1], dh[2], dh[3]});
      const bf16x8 Al = asbf8((u32x4){dl[0], dl[1], dl[2], dl[3]});
      const int kcb = (ks * 2 + kh2) * 128;
      #pragma unroll
      for (int jt = 0; jt < 4; ++jt) {
        const bf16x8 Bh = *(const bf16x8*)&w2h[(kcb + jt * 32 + col) * 8];
        const bf16x8 Bl = *(const bf16x8*)&w2l[(kcb + jt * 32 + col) * 8];
        f32x16 c = (ks == 0) ? zf : acc2[jt];
        c = __builtin_amdgcn_mfma_f32_32x32x16_bf16(Ah, Bh, c, 0, 0, 0);
        c = __builtin_amdgcn_mfma_f32_32x32x16_bf16(Ah, Bl, c, 0, 0, 0);
        c = __builtin_amdgcn_mfma_f32_32x32x16_bf16(Al, Bh, c, 0, 0, 0);
        acc2[jt] = c;
      }
    }

    // ---- running segmented max ----
    const int bA = __shfl(bi, 0);
    const int bB = __shfl(bi, 31);
    if (bA != run_b) {
      FLUSH(run_b, run_s);
      #pragma unroll
      for (int jt = 0; jt < 4; ++jt) run_s[jt] = -3.0e38f;
      run_b = bA;
    }
    if (bA == bB) {
      // whole tile one batch (clamped tail rows duplicate point N-1: harmless)
      #pragma unroll
      for (int jt = 0; jt < 4; ++jt) {
        const f32x16 a = acc2[jt];
        float m = fmaxf(fmaxf(fmaxf(a[0], a[1]), fmaxf(a[2], a[3])),
                        fmaxf(fmaxf(a[4], a[5]), fmaxf(a[6], a[7])));
        const float m2 = fmaxf(fmaxf(fmaxf(a[8], a[9]), fmaxf(a[10], a[11])),
                               fmaxf(fmaxf(a[12], a[13]), fmaxf(a[14], a[15])));
        m = fmaxf(m, m2);
        m = fmaxf(m, __shfl_xor(m, 32));
        run_s[jt] = fmaxf(run_s[jt], m);
      }
    } else {
      int pbi[16];
      #pragma unroll
      for (int r = 0; r < 16; ++r) {
        const int rr = (r & 3) + ((r >> 2) << 3) + (kh2 << 2);
        pbi[r] = __shfl(bi, rr);
      }
      for (int b = bA; b <= bB; ++b) {
        float m[4];
        #pragma unroll
        for (int jt = 0; jt < 4; ++jt) {
          float mm = -3.0e38f;
          #pragma unroll
          for (int r = 0; r < 16; ++r)
            if (pbi[r] == b) mm = fmaxf(mm, acc2[jt][r]);
          mm = fmaxf(mm, __shfl_xor(mm, 32));
          if (b == bA) mm = fmaxf(mm, run_s[jt]);
          m[jt] = mm;
        }
        if (b < bB) {
          FLUSH(b, m);
        } else {
          #pragma unroll
          for (int jt = 0; jt < 4; ++jt) run_s[jt] = m[jt];
        }
      }
      run_b = bB;
    }
  }
  FLUSH(run_b, run_s);
}

// ---------------- decision MLP: [B,132] @ W3 -> lrelu -> @ W4 + b4 ----------------
__global__ __launch_bounds__(128) void sc_final(
    const unsigned* __restrict__ gf, const float* __restrict__ cond,
    const float* __restrict__ W3, const float* __restrict__ b3,
    const float* __restrict__ W4, const float* __restrict__ b4,
    float* __restrict__ out, int B) {
  __shared__ __align__(16) float w3t[128 * 132];  // [j][k]
  __shared__ float b3s[128], w4s[128];
  __shared__ __align__(16) float din[8 * 132];
  __shared__ float wred[16];
  const int t = threadIdx.x;
  for (int k = 0; k < 132; ++k) w3t[t * 132 + k] = W3[k * 128 + t];
  b3s[t] = b3[t];
  w4s[t] = W4[t];
  __syncthreads();

  const int nocts = (B + 7) >> 3;
  for (int oc = blockIdx.x; oc < nocts; oc += gridDim.x) {
    const int rbase = oc << 3;
    #pragma unroll
    for (int r = 0; r < 8; ++r) {
      const int row = rbase + r;
      if (row < B) {
        din[r * 132 + t] = mono2f(gf[row * 128 + t]);
        if (t < 4) din[r * 132 + 128 + t] = cond[row * 4 + t];
      }
    }
    __syncthreads();
    float a8[8];
    #pragma unroll
    for (int r = 0; r < 8; ++r) a8[r] = b3s[t];
    for (int kg = 0; kg < 33; ++kg) {
      const f32x4 wv = *(const f32x4*)&w3t[t * 132 + kg * 4];
      #pragma unroll
      for (int r = 0; r < 8; ++r) {
        const f32x4 dv = *(const f32x4*)&din[r * 132 + kg * 4];
        a8[r] += wv[0] * dv[0] + wv[1] * dv[1] + wv[2] * dv[2] + wv[3] * dv[3];
      }
    }
    const float w4v = w4s[t];
    #pragma unroll
    for (int r = 0; r < 8; ++r) a8[r] = lrelu(a8[r]) * w4v;
    const int lane = t & 63;
    const int wv_ = t >> 6;
    #pragma unroll
    for (int r = 0; r < 8; ++r) {
      float s = a8[r];
      s += __shfl_xor(s, 1);  s += __shfl_xor(s, 2);
      s += __shfl_xor(s, 4);  s += __shfl_xor(s, 8);
      s += __shfl_xor(s, 16); s += __shfl_xor(s, 32);
      if (lane == 0) wred[wv_ * 8 + r] = s;
    }
    __syncthreads();
    if (t < 8) {
      const int row = rbase + t;
      if (row < B) out[row] = wred[t] + wred[8 + t] + b4[0];
    }
    __syncthreads();
  }
}

extern "C" void kernel_launch(void* const* d_in, const int* in_sizes, int n_in,
                              void* d_out, int out_size, void* d_ws, size_t ws_size,
                              hipStream_t stream) {
  const float* muons = (const float*)d_in[0];
  const int* bidx = (const int*)d_in[1];
  const float* cond = (const float*)d_in[2];
  const float* W1 = (const float*)d_in[4];
  const float* b1 = (const float*)d_in[5];
  const float* W2 = (const float*)d_in[6];
  const float* b2 = (const float*)d_in[7];
  const float* W3 = (const float*)d_in[8];
  const float* b3 = (const float*)d_in[9];
  const float* W4 = (const float*)d_in[10];
  const float* b4 = (const float*)d_in[11];
  float* out = (float*)d_out;
  const int N = in_sizes[1];
  const int B = out_size;
  unsigned* gf = (unsigned*)d_ws;  // B*128 mono-encoded uints (8 MB)

  const int total4 = (B * 128) / 4;
  sc_init<<<(total4 + 255) / 256, 256, 0, stream>>>(gf, total4);

  const int nblocks = 1024;
  const int nwaves = nblocks * 4;
  const int cpw = (((N + nwaves - 1) / nwaves) + 31) & ~31;  // points per wave, ×32
  sc_main<<<nblocks, 256, 0, stream>>>(muons, bidx, cond, W1, b1, W2, b2, gf, N, cpw);
  sc_final<<<1024, 128, 0, stream>>>(gf, cond, W3, b3, W4, b4, out, B);
  (void)n_in; (void)ws_size;
}

// Round 4
// 304.882 us; speedup vs baseline: 2.4634x; 2.4634x over previous
//
#include <hip/hip_runtime.h>

typedef float f32x4 __attribute__((ext_vector_type(4)));
typedef float f32x16 __attribute__((ext_vector_type(16)));
typedef __bf16 bf16x8 __attribute__((ext_vector_type(8)));
typedef unsigned u32x4 __attribute__((ext_vector_type(4)));

__device__ __forceinline__ unsigned f2mono(float f) {
  unsigned u = __float_as_uint(f);
  return (u & 0x80000000u) ? ~u : (u | 0x80000000u);
}
__device__ __forceinline__ float mono2f(unsigned u) {
  return (u & 0x80000000u) ? __uint_as_float(u & 0x7fffffffu) : __uint_as_float(~u);
}
__device__ __forceinline__ float lrelu(float x) { return fmaxf(x, 0.2f * x); }
__device__ __forceinline__ unsigned pkhh(unsigned a, unsigned b) {
  return (a >> 16) | (b & 0xffff0000u);
}
__device__ __forceinline__ bf16x8 asbf8(u32x4 u) { return __builtin_bit_cast(bf16x8, u); }
__device__ __forceinline__ float truncbf(float x, unsigned& hbits) {
  hbits = __float_as_uint(x) & 0xffff0000u;
  return __uint_as_float(hbits);
}

// ---------------- init: global_feats = mono(-1e9) ----------------
__global__ void sc_init(unsigned* __restrict__ gf, int total4) {
  int i = blockIdx.x * blockDim.x + threadIdx.x;
  if (i < total4) {
    unsigned m = f2mono(-1.0e9f);
    ((uint4*)gf)[i] = make_uint4(m, m, m, m);
  }
}

// ---- fused: gather + L1(MFMA) + L2(split-bf16 MFMA, two j-half passes) + running seg-max ----
// Each wave owns ONE contiguous chunk of CPW points. Running per-feature max in
// registers; flush on batch transition. Interior batches -> plain store;
// boundary batches -> atomicMax. Two j-half passes keep peak VGPR ~110 (no spill).
__global__ __launch_bounds__(256, 2) void sc_main(
    const float* __restrict__ muons, const int* __restrict__ bidx,
    const float* __restrict__ cond, const float* __restrict__ W1,
    const float* __restrict__ b1, const float* __restrict__ W2,
    const float* __restrict__ b2, unsigned* __restrict__ gf, int N, int CPW) {
  __shared__ __align__(16) __bf16 w2h[8192];  // [kc=8][j=128][e=8] blocked, linear reads
  __shared__ __align__(16) __bf16 w2l[8192];
  __shared__ __align__(16) __bf16 w1e[2048];  // [kc=4][j=64][e=8] extended W1 (hi|hi|lo|bias)

  const int t = threadIdx.x;
  const int w = t >> 6;
  const int lane = t & 63;
  const int col = lane & 31;
  const int kh2 = lane >> 5;

  // ---- one-time weight staging ----
  {
    const int j = t & 127, kh = t >> 7;
    for (int kk = 0; kk < 32; ++kk) {
      const int k = kh * 32 + kk;
      const float v = W2[k * 128 + j];
      const __bf16 hb = (__bf16)v;
      const __bf16 lb = (__bf16)(v - (float)hb);
      const int idx = ((k >> 3) * 128 + j) * 8 + (k & 7);
      w2h[idx] = hb;
      w2l[idx] = lb;
    }
  }
  {
    // extended A1[j][k']: k'=0..6 W1h, 7..13 W1h, 14..20 W1l, 21 b1h, 22 b1l, else 0
    const int j = t & 63, kc = t >> 6;
    for (int e = 0; e < 8; ++e) {
      const int kp = kc * 8 + e;
      float val = 0.0f;
      unsigned hb;
      if (kp < 7)        { val = truncbf(W1[kp * 64 + j], hb); }
      else if (kp < 14)  { val = truncbf(W1[(kp - 7) * 64 + j], hb); }
      else if (kp < 21)  { float x = W1[(kp - 14) * 64 + j]; val = x - truncbf(x, hb); }
      else if (kp == 21) { val = truncbf(b1[j], hb); }
      else if (kp == 22) { float x = b1[j]; val = x - truncbf(x, hb); }
      w1e[(kc * 64 + j) * 8 + e] = (__bf16)val;
    }
  }
  __syncthreads();

  // persistent per-lane statics (small!)
  float b2v[4];
  #pragma unroll
  for (int jt = 0; jt < 4; ++jt) b2v[jt] = b2[jt * 32 + col];
  f32x16 zf;
  #pragma unroll
  for (int e = 0; e < 16; ++e) zf[e] = 0.0f;

  // ---- chunk setup ----
  const int gwave = blockIdx.x * 4 + w;
  const int start = gwave * CPW;
  if (start >= N) return;
  const int end = min(start + CPW, N);
  const int prevb = (start == 0) ? -1 : bidx[start - 1];
  const int nextb = (end >= N) ? -1 : bidx[end];
  int run_b = bidx[start];
  float run_s[4];
  #pragma unroll
  for (int jt = 0; jt < 4; ++jt) run_s[jt] = -3.0e38f;

  auto FLUSH2 = [&](int b, int jtb, float m0, float m1) {
    const bool interior = (b != prevb) && (b != nextb);
    if (lane < 32) {
      if (m0 > -2.9e38f) {
        const unsigned enc = f2mono(lrelu(m0 + b2v[jtb]));
        unsigned* addr = &gf[b * 128 + jtb * 32 + col];
        if (interior) *addr = enc; else atomicMax(addr, enc);
      }
      if (m1 > -2.9e38f) {
        const unsigned enc = f2mono(lrelu(m1 + b2v[jtb + 1]));
        unsigned* addr = &gf[b * 128 + (jtb + 1) * 32 + col];
        if (interior) *addr = enc; else atomicMax(addr, enc);
      }
    }
  };

  for (int pbase = start; pbase < end; pbase += 32) {
    const int pc = min(pbase + col, N - 1);
    const int bi = bidx[pc];

    // ---- load + decompose point inputs ----
    float in[7];
    in[0] = muons[pc * 3 + 0];
    in[1] = muons[pc * 3 + 1];
    in[2] = muons[pc * 3 + 2];
    const f32x4 c4 = *(const f32x4*)&cond[bi * 4];
    in[3] = c4.x; in[4] = c4.y; in[5] = c4.z; in[6] = c4.w;
    unsigned hu[7], lu[7];
    #pragma unroll
    for (int f = 0; f < 7; ++f) {
      const float hf = truncbf(in[f], hu[f]);
      lu[f] = __float_as_uint(in[f] - hf);
    }
    // B1 fragments (col = point): K' = [inh(7) | inl(7) | inh(7) | b-slots | 0]
    u32x4 f0a = { pkhh(hu[0], hu[1]), pkhh(hu[2], hu[3]), pkhh(hu[4], hu[5]), pkhh(hu[6], lu[0]) };
    u32x4 f0b = { pkhh(lu[1], lu[2]), pkhh(lu[3], lu[4]), pkhh(lu[5], lu[6]), f0a.x };
    u32x4 f1a = { f0a.y, f0a.z, (hu[6] >> 16) | 0x3F800000u, 0x00003F80u };
    u32x4 bf0u, bf1u;
    #pragma unroll
    for (int e2 = 0; e2 < 4; ++e2) {
      bf0u[e2] = kh2 ? f0b[e2] : f0a[e2];
      bf1u[e2] = kh2 ? 0u : f1a[e2];
    }
    const bf16x8 bfr0 = asbf8(bf0u), bfr1 = asbf8(bf1u);

    // ---- layer1: D1[j][p], bias folded; W1 frags re-read from LDS (saves VGPRs) ----
    f32x16 acc0, acc1;
    {
      const bf16x8 wf00 = *(const bf16x8*)&w1e[((kh2 * 64) + col) * 8];
      const bf16x8 wf01 = *(const bf16x8*)&w1e[(((2 + kh2) * 64) + col) * 8];
      acc0 = __builtin_amdgcn_mfma_f32_32x32x16_bf16(wf00, bfr0, zf, 0, 0, 0);
      acc0 = __builtin_amdgcn_mfma_f32_32x32x16_bf16(wf01, bfr1, acc0, 0, 0, 0);
      const bf16x8 wf10 = *(const bf16x8*)&w1e[((kh2 * 64) + 32 + col) * 8];
      const bf16x8 wf11 = *(const bf16x8*)&w1e[(((2 + kh2) * 64) + 32 + col) * 8];
      acc1 = __builtin_amdgcn_mfma_f32_32x32x16_bf16(wf10, bfr0, zf, 0, 0, 0);
      acc1 = __builtin_amdgcn_mfma_f32_32x32x16_bf16(wf11, bfr1, acc1, 0, 0, 0);
    }

    // ---- lrelu + decompose h into packed bf16 pair-dwords (acc0/acc1 die here) ----
    unsigned pkh_[16], pkl_[16];
    #pragma unroll
    for (int m = 0; m < 8; ++m) {
      const float x0 = lrelu(acc0[2 * m]), x1 = lrelu(acc0[2 * m + 1]);
      unsigned h0, h1;
      const float hf0 = truncbf(x0, h0), hf1 = truncbf(x1, h1);
      const unsigned l0 = __float_as_uint(x0 - hf0), l1 = __float_as_uint(x1 - hf1);
      pkh_[m] = (h0 >> 16) | h1;
      pkl_[m] = (l0 >> 16) | (l1 & 0xffff0000u);
    }
    #pragma unroll
    for (int m = 0; m < 8; ++m) {
      const float x0 = lrelu(acc1[2 * m]), x1 = lrelu(acc1[2 * m + 1]);
      unsigned h0, h1;
      const float hf0 = truncbf(x0, h0), hf1 = truncbf(x1, h1);
      const unsigned l0 = __float_as_uint(x0 - hf0), l1 = __float_as_uint(x1 - hf1);
      pkh_[8 + m] = (h0 >> 16) | h1;
      pkl_[8 + m] = (l0 >> 16) | (l1 & 0xffff0000u);
    }

    // ---- batch transition flush (uses run_s only) ----
    const int bA = __shfl(bi, 0);
    const int bB = __shfl(bi, 31);
    if (bA != run_b) {
      FLUSH2(run_b, 0, run_s[0], run_s[1]);
      FLUSH2(run_b, 2, run_s[2], run_s[3]);
      #pragma unroll
      for (int jt = 0; jt < 4; ++jt) run_s[jt] = -3.0e38f;
      run_b = bA;
    }
    const bool fast = (bA == bB);

    // ---- layer2 in two j-half passes (acc = 32 regs per pass) ----
    #pragma unroll
    for (int jh = 0; jh < 2; ++jh) {
      f32x16 a2_0, a2_1;
      #pragma unroll
      for (int ks = 0; ks < 4; ++ks) {
        const int base = (ks >> 1) * 8;
        const int c0 = (ks & 1) * 4;
        unsigned dh[4], dl[4];
        #pragma unroll
        for (int cc = 0; cc < 2; ++cc) {
          {
            const unsigned plo = pkh_[base + c0 + cc];
            const unsigned phi = pkh_[base + c0 + cc + 2];
            const unsigned x = kh2 ? plo : phi;
            const unsigned y = (unsigned)__shfl_xor((int)x, 32);
            dh[cc] = kh2 ? y : plo;
            dh[2 + cc] = kh2 ? phi : y;
          }
          {
            const unsigned plo = pkl_[base + c0 + cc];
            const unsigned phi = pkl_[base + c0 + cc + 2];
            const unsigned x = kh2 ? plo : phi;
            const unsigned y = (unsigned)__shfl_xor((int)x, 32);
            dl[cc] = kh2 ? y : plo;
            dl[2 + cc] = kh2 ? phi : y;
          }
        }
        const bf16x8 Ah = asbf8((u32x4){dh[0], dh[1], dh[2], dh[3]});
        const bf16x8 Al = asbf8((u32x4){dl[0], dl[1], dl[2], dl[3]});
        const int kcb = (ks * 2 + kh2) * 128;
        {
          const int jcol = (jh * 2 + 0) * 32 + col;
          const bf16x8 Bh = *(const bf16x8*)&w2h[(kcb + jcol) * 8];
          const bf16x8 Bl = *(const bf16x8*)&w2l[(kcb + jcol) * 8];
          f32x16 c = (ks == 0) ? zf : a2_0;
          c = __builtin_amdgcn_mfma_f32_32x32x16_bf16(Ah, Bh, c, 0, 0, 0);
          c = __builtin_amdgcn_mfma_f32_32x32x16_bf16(Ah, Bl, c, 0, 0, 0);
          c = __builtin_amdgcn_mfma_f32_32x32x16_bf16(Al, Bh, c, 0, 0, 0);
          a2_0 = c;
        }
        {
          const int jcol = (jh * 2 + 1) * 32 + col;
          const bf16x8 Bh = *(const bf16x8*)&w2h[(kcb + jcol) * 8];
          const bf16x8 Bl = *(const bf16x8*)&w2l[(kcb + jcol) * 8];
          f32x16 c = (ks == 0) ? zf : a2_1;
          c = __builtin_amdgcn_mfma_f32_32x32x16_bf16(Ah, Bh, c, 0, 0, 0);
          c = __builtin_amdgcn_mfma_f32_32x32x16_bf16(Ah, Bl, c, 0, 0, 0);
          c = __builtin_amdgcn_mfma_f32_32x32x16_bf16(Al, Bh, c, 0, 0, 0);
          a2_1 = c;
        }
      }

      // ---- reduce + running max for this j-half ----
      if (fast) {
        {
          float m = fmaxf(fmaxf(fmaxf(a2_0[0], a2_0[1]), fmaxf(a2_0[2], a2_0[3])),
                          fmaxf(fmaxf(a2_0[4], a2_0[5]), fmaxf(a2_0[6], a2_0[7])));
          const float m2 = fmaxf(fmaxf(fmaxf(a2_0[8], a2_0[9]), fmaxf(a2_0[10], a2_0[11])),
                                 fmaxf(fmaxf(a2_0[12], a2_0[13]), fmaxf(a2_0[14], a2_0[15])));
          m = fmaxf(m, m2);
          m = fmaxf(m, __shfl_xor(m, 32));
          run_s[jh * 2 + 0] = fmaxf(run_s[jh * 2 + 0], m);
        }
        {
          float m = fmaxf(fmaxf(fmaxf(a2_1[0], a2_1[1]), fmaxf(a2_1[2], a2_1[3])),
                          fmaxf(fmaxf(a2_1[4], a2_1[5]), fmaxf(a2_1[6], a2_1[7])));
          const float m2 = fmaxf(fmaxf(fmaxf(a2_1[8], a2_1[9]), fmaxf(a2_1[10], a2_1[11])),
                                 fmaxf(fmaxf(a2_1[12], a2_1[13]), fmaxf(a2_1[14], a2_1[15])));
          m = fmaxf(m, m2);
          m = fmaxf(m, __shfl_xor(m, 32));
          run_s[jh * 2 + 1] = fmaxf(run_s[jh * 2 + 1], m);
        }
      } else {
        int pbi[16];
        #pragma unroll
        for (int r = 0; r < 16; ++r) {
          const int rr = (r & 3) + ((r >> 2) << 3) + (kh2 << 2);
          pbi[r] = __shfl(bi, rr);
        }
        for (int b = bA; b <= bB; ++b) {
          float m0 = -3.0e38f, m1 = -3.0e38f;
          #pragma unroll
          for (int r = 0; r < 16; ++r)
            if (pbi[r] == b) { m0 = fmaxf(m0, a2_0[r]); m1 = fmaxf(m1, a2_1[r]); }
          m0 = fmaxf(m0, __shfl_xor(m0, 32));
          m1 = fmaxf(m1, __shfl_xor(m1, 32));
          if (b == bA) {
            m0 = fmaxf(m0, run_s[jh * 2 + 0]);
            m1 = fmaxf(m1, run_s[jh * 2 + 1]);
          }
          if (b < bB) {
            FLUSH2(b, jh * 2, m0, m1);
          } else {
            run_s[jh * 2 + 0] = m0;
            run_s[jh * 2 + 1] = m1;
          }
        }
      }
    }
    run_b = bB;
  }
  FLUSH2(run_b, 0, run_s[0], run_s[1]);
  FLUSH2(run_b, 2, run_s[2], run_s[3]);
}

// ---------------- decision MLP: [B,132] @ W3 -> lrelu -> @ W4 + b4 ----------------
__global__ __launch_bounds__(128) void sc_final(
    const unsigned* __restrict__ gf, const float* __restrict__ cond,
    const float* __restrict__ W3, const float* __restrict__ b3,
    const float* __restrict__ W4, const float* __restrict__ b4,
    float* __restrict__ out, int B) {
  __shared__ __align__(16) float w3t[128 * 132];  // [j][k]
  __shared__ float b3s[128], w4s[128];
  __shared__ __align__(16) float din[8 * 132];
  __shared__ float wred[16];
  const int t = threadIdx.x;
  for (int k = 0; k < 132; ++k) w3t[t * 132 + k] = W3[k * 128 + t];
  b3s[t] = b3[t];
  w4s[t] = W4[t];
  __syncthreads();

  const int nocts = (B + 7) >> 3;
  for (int oc = blockIdx.x; oc < nocts; oc += gridDim.x) {
    const int rbase = oc << 3;
    #pragma unroll
    for (int r = 0; r < 8; ++r) {
      const int row = rbase + r;
      if (row < B) {
        din[r * 132 + t] = mono2f(gf[row * 128 + t]);
        if (t < 4) din[r * 132 + 128 + t] = cond[row * 4 + t];
      }
    }
    __syncthreads();
    float a8[8];
    #pragma unroll
    for (int r = 0; r < 8; ++r) a8[r] = b3s[t];
    for (int kg = 0; kg < 33; ++kg) {
      const f32x4 wv = *(const f32x4*)&w3t[t * 132 + kg * 4];
      #pragma unroll
      for (int r = 0; r < 8; ++r) {
        const f32x4 dv = *(const f32x4*)&din[r * 132 + kg * 4];
        a8[r] += wv[0] * dv[0] + wv[1] * dv[1] + wv[2] * dv[2] + wv[3] * dv[3];
      }
    }
    const float w4v = w4s[t];
    #pragma unroll
    for (int r = 0; r < 8; ++r) a8[r] = lrelu(a8[r]) * w4v;
    const int lane = t & 63;
    const int wv_ = t >> 6;
    #pragma unroll
    for (int r = 0; r < 8; ++r) {
      float s = a8[r];
      s += __shfl_xor(s, 1);  s += __shfl_xor(s, 2);
      s += __shfl_xor(s, 4);  s += __shfl_xor(s, 8);
      s += __shfl_xor(s, 16); s += __shfl_xor(s, 32);
      if (lane == 0) wred[wv_ * 8 + r] = s;
    }
    __syncthreads();
    if (t < 8) {
      const int row = rbase + t;
      if (row < B) out[row] = wred[t] + wred[8 + t] + b4[0];
    }
    __syncthreads();
  }
}

extern "C" void kernel_launch(void* const* d_in, const int* in_sizes, int n_in,
                              void* d_out, int out_size, void* d_ws, size_t ws_size,
                              hipStream_t stream) {
  const float* muons = (const float*)d_in[0];
  const int* bidx = (const int*)d_in[1];
  const float* cond = (const float*)d_in[2];
  const float* W1 = (const float*)d_in[4];
  const float* b1 = (const float*)d_in[5];
  const float* W2 = (const float*)d_in[6];
  const float* b2 = (const float*)d_in[7];
  const float* W3 = (const float*)d_in[8];
  const float* b3 = (const float*)d_in[9];
  const float* W4 = (const float*)d_in[10];
  const float* b4 = (const float*)d_in[11];
  float* out = (float*)d_out;
  const int N = in_sizes[1];
  const int B = out_size;
  unsigned* gf = (unsigned*)d_ws;  // B*128 mono-encoded uints (8 MB)

  const int total4 = (B * 128) / 4;
  sc_init<<<(total4 + 255) / 256, 256, 0, stream>>>(gf, total4);

  const int nblocks = 1024;
  const int nwaves = nblocks * 4;
  const int cpw = (((N + nwaves - 1) / nwaves) + 31) & ~31;  // points per wave, ×32
  sc_main<<<nblocks, 256, 0, stream>>>(muons, bidx, cond, W1, b1, W2, b2, gf, N, cpw);
  sc_final<<<1024, 128, 0, stream>>>(gf, cond, W3, b3, W4, b4, out, B);
  (void)n_in; (void)ws_size;
}